// Round 5
// baseline (1157.393 us; speedup 1.0000x reference)
//
#include <hip/hip_runtime.h>
#include <hip/hip_bf16.h>

#define NN 16384

using f32x4  = __attribute__((ext_vector_type(4))) float;
using f32x2  = __attribute__((ext_vector_type(2))) float;
using bf16x8 = __attribute__((ext_vector_type(8))) __bf16;
using u16x8  = __attribute__((ext_vector_type(8))) unsigned short;

__device__ __forceinline__ void gload_lds16(const void* g, void* l) {
  __builtin_amdgcn_global_load_lds(
      (const __attribute__((address_space(1))) unsigned*)g,
      (__attribute__((address_space(3))) unsigned*)l, 16, 0, 0);
}

__device__ __forceinline__ unsigned short bf16r(float x) {
  return __builtin_bit_cast(unsigned short, (__bf16)x);
}

// f32 -> e4m3 (OCP), RNE, subnormals flushed to 0 (inputs |x| < 32 guaranteed).
__device__ __forceinline__ unsigned fp8_enc(float f) {
  unsigned u    = __float_as_uint(f);
  unsigned sign = (u >> 24) & 0x80u;
  unsigned mag  = u & 0x7FFFFFFFu;
  unsigned e32  = mag >> 23;
  unsigned keep = (mag >> 20) & 7u;
  unsigned rest = mag & 0xFFFFFu;
  unsigned r    = ((e32 - 120u) << 3) | keep;
  r += (rest > 0x80000u) || ((rest == 0x80000u) && (keep & 1u));
  if (e32 < 121u) r = 0u;        // |f| < 2^-6: flush (negligible for our data)
  return sign | r;
}

// 8 x e4m3 (packed uint2) -> 8 x bf16. Exact (e4m3 has 4 sig bits <= bf16's 8).
__device__ __forceinline__ u16x8 fp8x8_to_bf16x8(uint2 r) {
  f32x2 p0, p1, p2, p3;
  unsigned hx = r.x >> 16, hy = r.y >> 16;
  asm("v_cvt_pk_f32_fp8 %0, %1" : "=v"(p0) : "v"(r.x));
  asm("v_cvt_pk_f32_fp8 %0, %1" : "=v"(p1) : "v"(hx));
  asm("v_cvt_pk_f32_fp8 %0, %1" : "=v"(p2) : "v"(r.y));
  asm("v_cvt_pk_f32_fp8 %0, %1" : "=v"(p3) : "v"(hy));
  unsigned q0, q1, q2, q3;
  asm("v_cvt_pk_bf16_f32 %0, %1, %2" : "=v"(q0) : "v"(p0.x), "v"(p0.y));
  asm("v_cvt_pk_bf16_f32 %0, %1, %2" : "=v"(q1) : "v"(p1.x), "v"(p1.y));
  asm("v_cvt_pk_bf16_f32 %0, %1, %2" : "=v"(q2) : "v"(p2.x), "v"(p2.y));
  asm("v_cvt_pk_bf16_f32 %0, %1, %2" : "=v"(q3) : "v"(p3.x), "v"(p3.y));
  uint4 qq = {q0, q1, q2, q3};
  return __builtin_bit_cast(u16x8, qq);
}

// ---------------- zero the atomic accumulator --------------------------------
__global__ void zero_cs(float* __restrict__ csS) {
  if (threadIdx.x < 128) csS[threadIdx.x] = 0.f;
}

// ---------------- exact f32 colsums of seq1|seq2 -> csS[128] -----------------
__global__ void seqsum(const float* __restrict__ seq1, const float* __restrict__ seq2,
                       float* __restrict__ csS) {
  const int e = blockIdx.x >> 4, chunk = blockIdx.x & 15;
  const float* seq = e ? seq2 : seq1;
  const int g = threadIdx.x >> 4;
  const int q = threadIdx.x & 15;
  f32x4 acc = {};
  for (int i = 0; i < 64; ++i) {
    int r = chunk * 1024 + i * 16 + g;
    acc += *(const f32x4*)(seq + (long)r * 64 + q * 4);
  }
  __shared__ f32x4 red[256];
  red[threadIdx.x] = acc;
  __syncthreads();
  if (threadIdx.x < 64) {
    int d = threadIdx.x;
    float s = 0.f;
    #pragma unroll
    for (int g2 = 0; g2 < 16; ++g2) {
      f32x4 v = red[g2 * 16 + (d >> 2)];
      s += v[d & 3];
    }
    atomicAdd(&csS[e * 64 + d], s);
  }
}

// ---------------- seq1|seq2 -> S^T bf16 [128][16384] -------------------------
__global__ void prep_seq(const float* __restrict__ seq1, const float* __restrict__ seq2,
                         unsigned short* __restrict__ Shi) {
  const int tid = threadIdx.x;
  const int r0  = blockIdx.x * 64;
  const float* seq = blockIdx.y ? seq2 : seq1;
  __shared__ float t[64][65];
  #pragma unroll
  for (int i = 0; i < 16; ++i) {
    int row = i * 4 + (tid >> 6);
    t[row][tid & 63] = seq[(long)(r0 + row) * 64 + (tid & 63)];
  }
  __syncthreads();
  #pragma unroll
  for (int i = 0; i < 16; ++i) {
    int col = i * 4 + (tid >> 6);
    int rr  = tid & 63;
    Shi[(long)(blockIdx.y * 64 + col) * NN + r0 + rr] = bf16r(t[rr][col]);
  }
}

// ---------------- layer-1 GEMM + V' (fp8) emission ---------------------------
// P = ((0.5 J + V) @ X)^T / N; emits V' = 64*(N*adj - 0.5) as e4m3.
__launch_bounds__(256, 3)
__global__ void gemm1(const float* __restrict__ A,
                      const unsigned short* __restrict__ Xg,
                      const float* __restrict__ cs,
                      float* __restrict__ P,
                      unsigned char* __restrict__ Vg) {
  __shared__ unsigned short As[128 * 64];
  __shared__ unsigned short Xs[2][128 * 64];
  const int tid  = threadIdx.x;
  const int lane = tid & 63;
  const int wave = tid >> 6;
  const int wr = wave & 1;
  const int wc = wave >> 1;

  int bid = blockIdx.x;
  int lin = (bid & 7) * ((int)gridDim.x >> 3) + (bid >> 3);
  const int bx = lin & 127;
  const int bz = lin >> 7;                 // 0..3
  const int rtile = bx * 128;
  const int kbase = bz * 4096;

  const int arow0  = wave * 32 + (lane >> 3);
  const int ac     = lane & 7;
  const int awslot = ac ^ (lane >> 3);
  const float* aptr = A + (long)(rtile + arow0) * NN + kbase + ac * 8;
  unsigned char* vptr = Vg + (long)(rtile + arow0) * NN + kbase + ac * 8;

  const int cx = (lane & 7) ^ (lane >> 3);
  const unsigned short* xptr = Xg + (long)arow0 * NN + kbase + cx * 8;

  f32x4 acc[4][4] = {};
  f32x4 areg[4][2];

  #pragma unroll
  for (int t = 0; t < 4; ++t) {
    const float* ap = aptr + (long)t * 8 * NN;
    areg[t][0] = *(const f32x4*)ap;
    areg[t][1] = *(const f32x4*)(ap + 4);
    gload_lds16(xptr + (long)t * 8 * NN, &Xs[0][(wave * 4 + t) * 512]);
  }
  aptr += 64; xptr += 64;
  __syncthreads();

  int cur = 0;
  const int nsteps = 4096 / 64;
  for (int ks = 0; ks < nsteps; ++ks) {
    u16x8 wv[4];
    #pragma unroll
    for (int t = 0; t < 4; ++t) {
      unsigned lo = 0, hi = 0;
      #pragma unroll
      for (int i = 0; i < 8; ++i) {
        float a  = (i < 4) ? areg[t][0][i] : areg[t][1][i - 4];
        float vp = fmaf(a, 1048576.f, -32.f);     // V' = 64*(N*a - 0.5)
        wv[t][i] = bf16r(vp * 0.015625f);         // bf16(V) for this layer
        unsigned b = fp8_enc(vp);
        if (i < 4) lo |= b << (8 * i); else hi |= b << (8 * (i - 4));
      }
      uint2 pk = {lo, hi};
      *(uint2*)(vptr + (long)t * 8 * NN) = pk;    // emit V' fp8
    }
    vptr += 64;
    __syncthreads();                          // B1
    #pragma unroll
    for (int t = 0; t < 4; ++t)
      *(u16x8*)&As[(arow0 + t * 8) * 64 + awslot * 8] = wv[t];
    if (ks + 1 < nsteps) {
      #pragma unroll
      for (int t = 0; t < 4; ++t) {
        gload_lds16(xptr + (long)t * 8 * NN, &Xs[cur ^ 1][(wave * 4 + t) * 512]);
        const float* ap = aptr + (long)t * 8 * NN;
        areg[t][0] = *(const f32x4*)ap;
        areg[t][1] = *(const f32x4*)(ap + 4);
      }
      aptr += 64; xptr += 64;
    }
    __syncthreads();                          // B2
    #pragma unroll
    for (int mk = 0; mk < 2; ++mk) {
      bf16x8 af[4];
      #pragma unroll
      for (int ni = 0; ni < 4; ++ni) {
        int ar = wr * 64 + ni * 16 + (lane & 15);
        int slot = (mk * 4 + (lane >> 4)) ^ (ar & 7);
        af[ni] = *(const bf16x8*)&As[ar * 64 + slot * 8];
      }
      #pragma unroll
      for (int mi = 0; mi < 4; ++mi) {
        int xr = wc * 64 + mi * 16 + (lane & 15);
        int slot = (mk * 4 + (lane >> 4)) ^ (xr & 7);
        bf16x8 xf = *(const bf16x8*)&Xs[cur][xr * 64 + slot * 8];
        #pragma unroll
        for (int ni = 0; ni < 4; ++ni)
          acc[mi][ni] = __builtin_amdgcn_mfma_f32_16x16x32_bf16(xf, af[ni], acc[mi][ni], 0, 0, 0);
      }
    }
    cur ^= 1;
  }

  const float scl = 1.f / 16384.f;
  float* out = P + (long)bz * 128 * NN;
  #pragma unroll
  for (int mi = 0; mi < 4; ++mi) {
    int xc = wc * 64 + mi * 16 + ((lane >> 4) << 2);
    float dc[4];
    #pragma unroll
    for (int j = 0; j < 4; ++j) dc[j] = (bz == 0) ? 0.5f * cs[xc + j] : 0.f;
    #pragma unroll
    for (int ni = 0; ni < 4; ++ni) {
      int ar = rtile + wr * 64 + ni * 16 + (lane & 15);
      #pragma unroll
      for (int j = 0; j < 4; ++j)
        out[(long)(xc + j) * NN + ar] = (acc[mi][ni][j] + dc[j]) * scl;
    }
  }
}

// ---------------- layers-2/3 GEMM: P = ((0.5 J + V) @ X)^T / N ---------------
// Va = V' fp8 [NN][NN] (V' = 64 V). Xg = bf16 [ccols][NN]. cs = colsums of X.
__launch_bounds__(256, 3)
__global__ void gemm23(const unsigned char* __restrict__ Va,
                       const unsigned short* __restrict__ Xg,
                       const float* __restrict__ cs,
                       float* __restrict__ P, int ccols, int klen, int nY) {
  __shared__ unsigned short As[128 * 64];
  __shared__ unsigned short Xs[2][128 * 64];
  const int tid  = threadIdx.x;
  const int lane = tid & 63;
  const int wave = tid >> 6;
  const int wr = wave & 1;
  const int wc = wave >> 1;

  int bid = blockIdx.x;
  int lin = (bid & 7) * ((int)gridDim.x >> 3) + (bid >> 3);
  const int by = lin % nY;
  const int bx = (lin / nY) & 127;
  const int bz = lin / (nY * 128);
  const int rtile = bx * 128;
  const int ctile = by * 128;
  const int kbase = bz * klen;

  const int arow0  = wave * 32 + (lane >> 3);
  const int ac     = lane & 7;
  const int awslot = ac ^ (lane >> 3);
  const unsigned char* aptr = Va + (long)(rtile + arow0) * NN + kbase + ac * 8;

  const int cx = (lane & 7) ^ (lane >> 3);
  const unsigned short* xptr = Xg + (long)(ctile + arow0) * NN + kbase + cx * 8;

  f32x4 acc[4][4] = {};
  uint2 raw[4];

  #pragma unroll
  for (int t = 0; t < 4; ++t) {
    raw[t] = *(const uint2*)(aptr + (long)t * 8 * NN);
    gload_lds16(xptr + (long)t * 8 * NN, &Xs[0][(wave * 4 + t) * 512]);
  }
  aptr += 64; xptr += 64;
  __syncthreads();

  int cur = 0;
  const int nsteps = klen / 64;
  for (int ks = 0; ks < nsteps; ++ks) {
    u16x8 av[4];
    #pragma unroll
    for (int t = 0; t < 4; ++t)
      av[t] = fp8x8_to_bf16x8(raw[t]);        // lossless e4m3 -> bf16
    __syncthreads();                          // B1
    #pragma unroll
    for (int t = 0; t < 4; ++t)
      *(u16x8*)&As[(arow0 + t * 8) * 64 + awslot * 8] = av[t];
    if (ks + 1 < nsteps) {
      #pragma unroll
      for (int t = 0; t < 4; ++t) {
        gload_lds16(xptr + (long)t * 8 * NN, &Xs[cur ^ 1][(wave * 4 + t) * 512]);
        raw[t] = *(const uint2*)(aptr + (long)t * 8 * NN);
      }
      aptr += 64; xptr += 64;
    }
    __syncthreads();                          // B2
    #pragma unroll
    for (int mk = 0; mk < 2; ++mk) {
      bf16x8 af[4];
      #pragma unroll
      for (int ni = 0; ni < 4; ++ni) {
        int ar = wr * 64 + ni * 16 + (lane & 15);
        int slot = (mk * 4 + (lane >> 4)) ^ (ar & 7);
        af[ni] = *(const bf16x8*)&As[ar * 64 + slot * 8];
      }
      #pragma unroll
      for (int mi = 0; mi < 4; ++mi) {
        int xr = wc * 64 + mi * 16 + (lane & 15);
        int slot = (mk * 4 + (lane >> 4)) ^ (xr & 7);
        bf16x8 xf = *(const bf16x8*)&Xs[cur][xr * 64 + slot * 8];
        #pragma unroll
        for (int ni = 0; ni < 4; ++ni)
          acc[mi][ni] = __builtin_amdgcn_mfma_f32_16x16x32_bf16(xf, af[ni], acc[mi][ni], 0, 0, 0);
      }
    }
    cur ^= 1;
  }

  // out = (acc/64 + [z==0] 0.5*colsum_x) / N   (acc is V'@X = 64 V@X)
  const float scl = 1.f / 16384.f;
  float* out = P + (long)bz * ccols * NN;
  #pragma unroll
  for (int mi = 0; mi < 4; ++mi) {
    int xc = ctile + wc * 64 + mi * 16 + ((lane >> 4) << 2);
    float dc[4];
    #pragma unroll
    for (int j = 0; j < 4; ++j) dc[j] = (bz == 0) ? 0.5f * cs[xc + j] : 0.f;
    #pragma unroll
    for (int ni = 0; ni < 4; ++ni) {
      int ar = rtile + wr * 64 + ni * 16 + (lane & 15);
      #pragma unroll
      for (int j = 0; j < 4; ++j)
        out[(long)(xc + j) * NN + ar] = (acc[mi][ni][j] * 0.015625f + dc[j]) * scl;
    }
  }
}

// ---------------- post1a: H1^T (bf16) = relu((sum_z P) @ w1 + b1) ------------
__global__ void post1a(const float* __restrict__ P, const float* __restrict__ w1,
                       const float* __restrict__ b1, unsigned short* __restrict__ H1T) {
  const int r = blockIdx.x * 256 + threadIdx.x;
  const int e = blockIdx.y;
  float tv[64];
  #pragma unroll
  for (int k = 0; k < 64; ++k) {
    float s = 0.f;
    #pragma unroll
    for (int z = 0; z < 4; ++z)
      s += P[(long)(z * 128 + e * 64 + k) * NN + r];
    tv[k] = s;
  }
  for (int c = 0; c < 8; ++c) {
    const int j0 = c * 33;
    float acc[33];
    #pragma unroll
    for (int jj = 0; jj < 33; ++jj) acc[jj] = b1[j0 + jj];
    for (int k = 0; k < 64; ++k) {
      float tvk = tv[k];
      #pragma unroll
      for (int jj = 0; jj < 33; ++jj)
        acc[jj] = fmaf(tvk, w1[k * 264 + j0 + jj], acc[jj]);
    }
    #pragma unroll
    for (int jj = 0; jj < 33; ++jj)
      H1T[(long)(e * 264 + j0 + jj) * NN + r] = bf16r(fmaxf(acc[jj], 0.f));
  }
}

// ---------------- post1b: G (bf16) [2*192][NN] = (H1 @ w2)^T -----------------
__global__ void post1b(const unsigned short* __restrict__ H1T, const float* __restrict__ w2,
                       unsigned short* __restrict__ G) {
  const int r  = blockIdx.x * 256 + threadIdx.x;
  const int e  = blockIdx.y;
  const int q0 = blockIdx.z * 41;
  float acc[41] = {};
  for (int j = 0; j < 264; ++j) {
    float h = __uint_as_float((unsigned)H1T[(long)(e * 264 + j) * NN + r] << 16);
    #pragma unroll
    for (int qq = 0; qq < 41; ++qq)
      acc[qq] = fmaf(h, w2[j * 164 + q0 + qq], acc[qq]);
  }
  #pragma unroll
  for (int qq = 0; qq < 41; ++qq)
    G[(long)(e * 192 + q0 + qq) * NN + r] = bf16r(acc[qq]);
  if (blockIdx.z == 3) {
    for (int q = 164; q < 192; ++q)
      G[(long)(e * 192 + q) * NN + r] = 0;
  }
}

// ---------------- column sums of a bf16 [*][NN] matrix -----------------------
__global__ void colsum_bf16(const unsigned short* __restrict__ X, float* __restrict__ cs) {
  const int c = blockIdx.x;
  const unsigned short* row = X + (long)c * NN;
  float s = 0.f;
  for (int i = threadIdx.x; i < NN; i += 256)
    s += __uint_as_float((unsigned)row[i] << 16);
  __shared__ float red[256];
  red[threadIdx.x] = s;
  __syncthreads();
  for (int off = 128; off > 0; off >>= 1) {
    if (threadIdx.x < off) red[threadIdx.x] += red[threadIdx.x + off];
    __syncthreads();
  }
  if (threadIdx.x == 0) cs[c] = red[0];
}

// ---------------- post2: F (bf16) = (relu(sum_z P + b2) @ w3)^T --------------
__global__ void post2(const float* __restrict__ P, const float* __restrict__ w3,
                      const float* __restrict__ b2, unsigned short* __restrict__ F) {
  const int r  = blockIdx.x * 256 + threadIdx.x;
  const int e  = blockIdx.y;
  const int q0 = blockIdx.z * 32;
  float f[32] = {};
  for (int j = 0; j < 164; ++j) {
    float h = P[(long)(e * 192 + j) * NN + r] + P[(long)(384 + e * 192 + j) * NN + r] + b2[j];
    h = fmaxf(h, 0.f);
    #pragma unroll
    for (int q = 0; q < 32; ++q) f[q] = fmaf(h, w3[j * 64 + q0 + q], f[q]);
  }
  #pragma unroll
  for (int q = 0; q < 32; ++q)
    F[(long)(e * 64 + q0 + q) * NN + r] = bf16r(f[q]);
}

// ---------------- post3: H3^T = relu(sum_z P + b3) ---------------------------
__global__ void post3(const float* __restrict__ P, const float* __restrict__ b3,
                      float* __restrict__ H3T) {
  const int r = blockIdx.x * 256 + threadIdx.x;
  const int e = blockIdx.y;
  #pragma unroll
  for (int q = 0; q < 64; ++q) {
    float v = b3[q];
    #pragma unroll
    for (int z = 0; z < 4; ++z)
      v += P[(long)(z * 128 + e * 64 + q) * NN + r];
    H3T[(long)(e * 64 + q) * NN + r] = fmaxf(v, 0.f);
  }
}

// ---------------- colsum (f32) of encoder-1 H3 -------------------------------
__global__ void colsum(const float* __restrict__ H3T, float* __restrict__ sums) {
  const int c = blockIdx.x;
  const float* row = H3T + (long)c * NN;
  float s = 0.f;
  for (int i = threadIdx.x; i < NN; i += 256) s += row[i];
  __shared__ float red[256];
  red[threadIdx.x] = s;
  __syncthreads();
  for (int off = 128; off > 0; off >>= 1) {
    if (threadIdx.x < off) red[threadIdx.x] += red[threadIdx.x + off];
    __syncthreads();
  }
  if (threadIdx.x == 0) sums[c] = red[0];
}

// ---------------- c = sigmoid(mean), cw = wd @ c -----------------------------
__global__ void make_cw(const float* __restrict__ sums, const float* __restrict__ wd,
                        float* __restrict__ cw) {
  __shared__ float cv[64];
  const int t = threadIdx.x;
  cv[t] = 1.f / (1.f + expf(-sums[t] / 16384.f));
  __syncthreads();
  float a = 0.f;
  for (int d = 0; d < 64; ++d) a += cv[d] * wd[t * 64 + d];
  cw[t] = a;
}

// ---------------- scores -----------------------------------------------------
__global__ void score(const float* __restrict__ H3T, const float* __restrict__ cw,
                      const float* __restrict__ bdp, const float* __restrict__ sb1,
                      const float* __restrict__ sb2, float* __restrict__ out) {
  const int idx = blockIdx.x * 256 + threadIdx.x;
  const int e = idx >> 14, r = idx & (NN - 1);
  float acc = bdp[0] + (e ? sb2[r] : sb1[r]);
  const float* base = H3T + (long)e * 64 * NN + r;
  #pragma unroll
  for (int j = 0; j < 64; ++j) acc = fmaf(base[(long)j * NN], cw[j], acc);
  out[idx] = acc;
}

extern "C" void kernel_launch(void* const* d_in, const int* in_sizes, int n_in,
                              void* d_out, int out_size, void* d_ws, size_t ws_size,
                              hipStream_t stream) {
  const float* seq1 = (const float*)d_in[0];
  const float* seq2 = (const float*)d_in[1];
  const float* adj  = (const float*)d_in[2];
  const float* sb1  = (const float*)d_in[3];
  const float* sb2  = (const float*)d_in[4];
  const float* w1   = (const float*)d_in[5];
  const float* b1   = (const float*)d_in[6];
  const float* w2   = (const float*)d_in[7];
  const float* b2   = (const float*)d_in[8];
  const float* w3   = (const float*)d_in[9];
  const float* b3   = (const float*)d_in[10];
  const float* wd   = (const float*)d_in[11];
  const float* bd   = (const float*)d_in[12];
  float* out = (float*)d_out;

  // workspace (~366 MB of 4 GiB). V' fp8 persists through all layers.
  char* ws = (char*)d_ws;
  unsigned char*  Vg  = (unsigned char*)(ws + 0);             // 268,435,456
  unsigned short* Shi = (unsigned short*)(ws + 268435456);    //   4,194,304
  float*          Pp  = (float*)(ws + 272629760);             //  50,331,648 max
  unsigned short* G   = (unsigned short*)(ws + 322961408);    //  12,582,912
  unsigned short* H1T = (unsigned short*)(ws + 335544320);    //  17,301,504
  unsigned short* F   = (unsigned short*)(ws + 352845824);    //   4,194,304
  float*          H3T = (float*)(ws + 357040128);             //   8,388,608
  float*          csS = (float*)(ws + 365428736);             //         512
  float*          csG = (float*)(ws + 365429248);             //       1,536
  float*          csF = (float*)(ws + 365430784);             //         512
  float*          sums= (float*)(ws + 365431296);             //         256
  float*          cw  = (float*)(ws + 365431552);             //         256

  zero_cs    <<<1, 128, 0, stream>>>(csS);
  seqsum     <<<32, 256, 0, stream>>>(seq1, seq2, csS);
  prep_seq   <<<dim3(256, 2), 256, 0, stream>>>(seq1, seq2, Shi);
  gemm1      <<<512, 256, 0, stream>>>(adj, Shi, csS, Pp, Vg);
  post1a     <<<dim3(64, 2), 256, 0, stream>>>(Pp, w1, b1, H1T);
  post1b     <<<dim3(64, 2, 4), 256, 0, stream>>>(H1T, w2, G);
  colsum_bf16<<<384, 256, 0, stream>>>(G, csG);
  gemm23     <<<768, 256, 0, stream>>>(Vg, G, csG, Pp, 384, 8192, 3);
  post2      <<<dim3(64, 2, 2), 256, 0, stream>>>(Pp, w3, b2, F);
  colsum_bf16<<<128, 256, 0, stream>>>(F, csF);
  gemm23     <<<512, 256, 0, stream>>>(Vg, F, csF, Pp, 128, 4096, 1);
  post3      <<<dim3(64, 2), 256, 0, stream>>>(Pp, b3, H3T);
  colsum     <<<64, 256, 0, stream>>>(H3T, sums);
  make_cw    <<<1, 64, 0, stream>>>(sums, wd, cw);
  score      <<<128, 256, 0, stream>>>(H3T, cw, bd, sb1, sb2, out);
}